// Round 12
// baseline (543.625 us; speedup 1.0000x reference)
//
#include <hip/hip_runtime.h>
#include <hip/hip_bf16.h>

// Transducer joint: logits[b,t,u,v] = tanh(enc_proj[b,t,:]+dec_proj[b,u,:]+b1) @ W2 + b2
// B=4 T=256 U=128, ENC=DEC=512, INNER=512, VOCAB=2048
// R12 = R6 (best, 406us) + 0-conflict LDS swizzle + sc1 epilogue stores.
//   Theory: nt = no-allocate L2+L3 -> partial-line RMW at HBM (R9: WRITE 2.07x).
//   sc1 = device-scope: bypasses per-XCD L2 (no thrash, unlike plain/R10) but
//   allocates in 256MB L3, which assembles full lines -> unamplified writeback.

typedef __attribute__((ext_vector_type(4))) float f32x4;
typedef __attribute__((ext_vector_type(8))) __bf16 bf16x8;
typedef __attribute__((ext_vector_type(8))) unsigned short u16x8;

__device__ __forceinline__ float bf2f(unsigned short u) {
  unsigned int x = ((unsigned int)u) << 16;
  return __builtin_bit_cast(float, x);
}
__device__ __forceinline__ unsigned short f2bf(float f) {
  unsigned int x = __builtin_bit_cast(unsigned int, f);
  x += 0x7fff + ((x >> 16) & 1);   // RNE
  return (unsigned short)(x >> 16);
}
__device__ __forceinline__ float tanh_fast(float x) {
  float e = __expf(2.0f * x);
  return 1.0f - 2.0f * __builtin_amdgcn_rcpf(e + 1.0f);
}

typedef __attribute__((address_space(3))) unsigned int lds_u32;
typedef const __attribute__((address_space(1))) unsigned int glb_u32;
__device__ __forceinline__ void gl16(const void* g, void* l) {
  __builtin_amdgcn_global_load_lds((glb_u32*)g, (lds_u32*)l, 16, 0, 0);
}

// device-scope store: through per-XCD L2, allocates in L3 (line assembly)
__device__ __forceinline__ void store_sc1(float* p, f32x4 v) {
  asm volatile("global_store_dwordx4 %0, %1, off sc1" :: "v"(p), "v"(v) : "memory");
}

#define BAR __builtin_amdgcn_s_barrier()
#define LGKM0 asm volatile("s_waitcnt lgkmcnt(0)" ::: "memory")
#define VMCNT(n) asm volatile("s_waitcnt vmcnt(" #n ")" ::: "memory")
#define MEMPIN asm volatile("" ::: "memory")

// ---------------- Pass 1: proj (x-in-LDS broadcast GEMM) ----------------
__global__ __launch_bounds__(512) void proj8_kernel(
    const float* __restrict__ enc, const float* __restrict__ dec,
    const float* __restrict__ W1, const float* __restrict__ b1,
    float* __restrict__ enc_proj, unsigned short* __restrict__ decb) {
  __shared__ float xs[8][512];
  const int bid = blockIdx.x;
  const bool isenc = bid < 128;
  const int rows0 = (isenc ? bid : bid - 128) * 8;
  const float* src = (isenc ? enc : dec) + (size_t)rows0 * 512;
  const int tid = threadIdx.x;
#pragma unroll
  for (int j = 0; j < 2; ++j) {
    int v = j * 512 + tid;
    int row = v >> 7;
    int c4 = (v & 127) << 2;
    *(f32x4*)&xs[row][c4] = *(const f32x4*)&src[(size_t)row * 512 + c4];
  }
  __syncthreads();
  const int h = tid;
  const float* wp = W1 + (isenc ? 0 : (size_t)512 * 512) + h;
  float acc[8];
  float init = isenc ? 0.f : b1[h];
#pragma unroll
  for (int r = 0; r < 8; ++r) acc[r] = init;
#pragma unroll 4
  for (int k = 0; k < 512; ++k) {
    float wv = wp[(size_t)k * 512];
#pragma unroll
    for (int r = 0; r < 8; ++r) acc[r] = fmaf(xs[r][k], wv, acc[r]);
  }
  if (isenc) {
#pragma unroll
    for (int r = 0; r < 8; ++r) enc_proj[(size_t)(rows0 + r) * 512 + h] = acc[r];
  } else {
#pragma unroll
    for (int r = 0; r < 8; ++r) decb[(size_t)(rows0 + r) * 512 + h] = f2bf(acc[r]);
  }
}

// ---------------- Pass 2: W2 [512][2048] fp32 -> W2t [2048][512] bf16 ----------------
__global__ __launch_bounds__(256) void w2t_kernel(const float* __restrict__ W2,
                                                  unsigned short* __restrict__ W2t) {
  __shared__ unsigned short tile[32][33];
  int bn = blockIdx.x;
  int bk = blockIdx.y;
  int tx = threadIdx.x & 31;
  int ty = threadIdx.x >> 5;
#pragma unroll
  for (int i = 0; i < 32; i += 8)
    tile[ty + i][tx] = f2bf(W2[(size_t)(bk * 32 + ty + i) * 2048 + bn * 32 + tx]);
  __syncthreads();
#pragma unroll
  for (int i = 0; i < 32; i += 8)
    W2t[(size_t)(bn * 32 + ty + i) * 512 + bk * 32 + tx] = tile[tx][ty + i];
}

// ---------------- Pass 3: H[m][h] = tanh(encp[bt][h] + decb[bu][h]) bf16 ----------------
__global__ __launch_bounds__(256) void h_kernel(
    const float* __restrict__ encp, const unsigned short* __restrict__ decb,
    unsigned short* __restrict__ Hout) {
  int gid = blockIdx.x * 256 + threadIdx.x;
  int m = gid >> 6;
  int hc = (gid & 63) << 3;
  int bt = m >> 7;
  int bu = ((m >> 15) << 7) | (m & 127);
  u16x8 dv = *(const u16x8*)(decb + (size_t)bu * 512 + hc);
  f32x4 e0 = *(const f32x4*)(encp + (size_t)bt * 512 + hc);
  f32x4 e1 = *(const f32x4*)(encp + (size_t)bt * 512 + hc + 4);
  u16x8 hv;
#pragma unroll
  for (int j = 0; j < 4; ++j) hv[j] = f2bf(tanh_fast(bf2f(dv[j]) + e0[j]));
#pragma unroll
  for (int j = 0; j < 4; ++j) hv[4 + j] = f2bf(tanh_fast(bf2f(dv[4 + j]) + e1[j]));
  *(u16x8*)(Hout + (size_t)m * 512 + hc) = hv;
}

// ---------------- Pass 4: BM=256 BN=128 BK=32 ring-3 GEMM ----------------
// LDS per slot: A [256][32] + B [128][32] bf16 = 24 KB; ring-3 = 72 KB ->
// 2 blocks/CU. 8 waves (4M x 2N), wave-tile 64x64. Swizzle: chunk c of row r
// at c ^ ((r>>1)&3) (PMC: 0 conflicts). Phase t: vmcnt(3) -> barrier ->
// ds_read 8 -> stage t+2 -> 16 MFMA. Epilogue: LDS transpose + sc1 stores.

__global__ __launch_bounds__(512, 4) void gemm32_kernel(
    const unsigned short* __restrict__ H,     // [131072][512] bf16
    const unsigned short* __restrict__ W2t,   // [2048][512] bf16
    const float* __restrict__ b2,             // [2048]
    float* __restrict__ out) {                // [131072][2048] fp32
  __shared__ __align__(1024) char smem[73728];

  const int bid = blockIdx.x;
  const int wg = (bid & 7) * 1024 + (bid >> 3);  // 8192%8==0 -> bijective
  const int my = wg >> 4;    // 0..511 (A panel; 16 consecutive wg share it)
  const int ny = wg & 15;    // 0..15

  const int tid = threadIdx.x;
  const int lane = tid & 63;
  const int w = tid >> 6;    // 0..7
  const int wm = w >> 1;     // 0..3
  const int wn = w & 1;      // 0..1
  const int fr = lane & 15;
  const int fq = lane >> 4;

  const char* ha = (const char*)(H + (size_t)my * 256 * 512);    // panel, row=1024B
  const char* wb = (const char*)(W2t + (size_t)ny * 128 * 512);  // panel, row=1024B

  // per-thread gl16 source offsets (dest linear; src chunk pre-swizzled)
  size_t srcA[2], srcB;
#pragma unroll
  for (int p = 0; p < 2; ++p) {
    int d = p * 8192 + w * 1024 + lane * 16;
    int r = d >> 6;
    int c = (d >> 4) & 3;
    srcA[p] = (size_t)r * 1024 + (size_t)((c ^ ((r >> 1) & 3)) << 4);
  }
  {
    int d = w * 1024 + lane * 16;
    int r = d >> 6;
    int c = (d >> 4) & 3;
    srcB = (size_t)r * 1024 + (size_t)((c ^ ((r >> 1) & 3)) << 4);
  }

  // ds_read offsets (within slot)
  const int swz = (fq ^ ((fr >> 1) & 3)) << 4;
  const int ldsA = (wm * 64 + fr) * 64 + swz;            // + mi*1024
  const int ldsB = 16384 + (wn * 64 + fr) * 64 + swz;    // + ni*1024

  f32x4 acc[4][4];
#pragma unroll
  for (int i = 0; i < 4; ++i)
#pragma unroll
    for (int j = 0; j < 4; ++j) acc[i][j] = (f32x4){0.f, 0.f, 0.f, 0.f};

#define STAGE(tt, slot)                                         \
  do {                                                          \
    char* sl = smem + (slot)*24576;                             \
    gl16(ha + srcA[0] + (tt)*64, sl + w * 1024);                \
    gl16(ha + srcA[1] + (tt)*64, sl + 8192 + w * 1024);         \
    gl16(wb + srcB + (tt)*64, sl + 16384 + w * 1024);           \
  } while (0)

  // prologue: batch 0 -> slot 0, batch 1 -> slot 1
  STAGE(0, 0);
  STAGE(1, 1);

#pragma unroll
  for (int t = 0; t < 16; ++t) {
    if (t < 15) { VMCNT(3); } else { VMCNT(0); }
    BAR; MEMPIN;
    const char* As = smem + (t % 3) * 24576;
    bf16x8 a4[4], b4[4];
#pragma unroll
    for (int mi = 0; mi < 4; ++mi) a4[mi] = *(const bf16x8*)(As + ldsA + mi * 1024);
#pragma unroll
    for (int ni = 0; ni < 4; ++ni) b4[ni] = *(const bf16x8*)(As + ldsB + ni * 1024);
    if (t + 2 < 16) STAGE(t + 2, (t + 2) % 3);
    LGKM0;
    __builtin_amdgcn_s_setprio(1);
#pragma unroll
    for (int mi = 0; mi < 4; ++mi)
#pragma unroll
      for (int ni = 0; ni < 4; ++ni)
        acc[mi][ni] = __builtin_amdgcn_mfma_f32_16x16x32_bf16(
            a4[mi], b4[ni], acc[mi][ni], 0, 0, 0);
    __builtin_amdgcn_s_setprio(0);
  }
  BAR; MEMPIN;   // protect epilogue LDS reuse

  // ---- epilogue: +b2, per-wave LDS transpose, sc1 stores ----
  float* lslice = (float*)(smem + w * 4352);   // 16 rows x 68 f32
  const size_t orow0 = (size_t)my * 256 + wm * 64;
  const int ncol0 = ny * 128 + wn * 64;
  float bv[4];
#pragma unroll
  for (int ni = 0; ni < 4; ++ni) bv[ni] = b2[ncol0 + ni * 16 + fr];

  const int rrow = lane >> 4;
  const int rcol = (lane & 15) * 4;
#pragma unroll
  for (int mi = 0; mi < 4; ++mi) {
#pragma unroll
    for (int ni = 0; ni < 4; ++ni)
#pragma unroll
      for (int r = 0; r < 4; ++r)
        lslice[(fq * 4 + r) * 68 + ni * 16 + fr] = acc[mi][ni][r] + bv[ni];
#pragma unroll
    for (int j = 0; j < 4; ++j) {
      int row = j * 4 + rrow;
      f32x4 v = *(const f32x4*)&lslice[row * 68 + rcol];
      store_sc1(&out[(orow0 + mi * 16 + row) * 2048 + ncol0 + rcol], v);
    }
  }
#undef STAGE
}

extern "C" void kernel_launch(void* const* d_in, const int* in_sizes, int n_in,
                              void* d_out, int out_size, void* d_ws, size_t ws_size,
                              hipStream_t stream) {
  const float* enc = (const float*)d_in[0];
  const float* dec = (const float*)d_in[1];
  const float* W1  = (const float*)d_in[2];
  const float* b1  = (const float*)d_in[3];
  const float* W2  = (const float*)d_in[4];
  const float* b2  = (const float*)d_in[5];
  float* out = (float*)d_out;

  char* ws = (char*)d_ws;
  float* enc_proj = (float*)ws;                                    // 2 MB
  unsigned short* decb = (unsigned short*)(ws + (2u << 20));       // 512 KB
  unsigned short* W2t  = (unsigned short*)(ws + (2u << 20) + (512u << 10)); // 2 MB
  unsigned short* Hbuf = (unsigned short*)(ws + (8u << 20));       // 134.25 MB

  proj8_kernel<<<192, 512, 0, stream>>>(enc, dec, W1, b1, enc_proj, decb);
  w2t_kernel<<<dim3(64, 16), 256, 0, stream>>>(W2, W2t);
  h_kernel<<<32768, 256, 0, stream>>>(enc_proj, decb, Hbuf);
  gemm32_kernel<<<8192, 512, 0, stream>>>(Hbuf, W2t, b2, out);
}

// Round 13
// 398.733 us; speedup vs baseline: 1.3634x; 1.3634x over previous
//
#include <hip/hip_runtime.h>
#include <hip/hip_bf16.h>

// Transducer joint: logits[b,t,u,v] = tanh(enc_proj[b,t,:]+dec_proj[b,u,:]+b1) @ W2 + b2
// B=4 T=256 U=128, ENC=DEC=512, INNER=512, VOCAB=2048
// R13 = R6 core (best, 406us) with tile swapped to BM=128 x BN=256 so the
// epilogue can emit 1024B-contiguous nt stores (R6: 4x256B scattered per
// instr; R9 measured nt WRITE_SIZE 2.07x on 512B segments -> test whether
// amplification is segment-size-sensitive). Cooperative chunked epilogue
// through one LDS buffer. Staging ring + vmcnt ledger unchanged.

typedef __attribute__((ext_vector_type(4))) float f32x4;
typedef __attribute__((ext_vector_type(8))) __bf16 bf16x8;
typedef __attribute__((ext_vector_type(8))) unsigned short u16x8;

__device__ __forceinline__ float bf2f(unsigned short u) {
  unsigned int x = ((unsigned int)u) << 16;
  return __builtin_bit_cast(float, x);
}
__device__ __forceinline__ unsigned short f2bf(float f) {
  unsigned int x = __builtin_bit_cast(unsigned int, f);
  x += 0x7fff + ((x >> 16) & 1);   // RNE
  return (unsigned short)(x >> 16);
}
__device__ __forceinline__ float tanh_fast(float x) {
  float e = __expf(2.0f * x);
  return 1.0f - 2.0f * __builtin_amdgcn_rcpf(e + 1.0f);
}

typedef __attribute__((address_space(3))) unsigned int lds_u32;
typedef const __attribute__((address_space(1))) unsigned int glb_u32;
__device__ __forceinline__ void gl16(const void* g, void* l) {
  __builtin_amdgcn_global_load_lds((glb_u32*)g, (lds_u32*)l, 16, 0, 0);
}

#define BAR __builtin_amdgcn_s_barrier()
#define LGKM0 asm volatile("s_waitcnt lgkmcnt(0)" ::: "memory")
#define VMCNT(n) asm volatile("s_waitcnt vmcnt(" #n ")" ::: "memory")
#define MEMPIN asm volatile("" ::: "memory")

// ---------------- Pass 1: proj (x-in-LDS broadcast GEMM) ----------------
__global__ __launch_bounds__(512) void proj8_kernel(
    const float* __restrict__ enc, const float* __restrict__ dec,
    const float* __restrict__ W1, const float* __restrict__ b1,
    float* __restrict__ enc_proj, unsigned short* __restrict__ decb) {
  __shared__ float xs[8][512];
  const int bid = blockIdx.x;
  const bool isenc = bid < 128;
  const int rows0 = (isenc ? bid : bid - 128) * 8;
  const float* src = (isenc ? enc : dec) + (size_t)rows0 * 512;
  const int tid = threadIdx.x;
#pragma unroll
  for (int j = 0; j < 2; ++j) {
    int v = j * 512 + tid;
    int row = v >> 7;
    int c4 = (v & 127) << 2;
    *(f32x4*)&xs[row][c4] = *(const f32x4*)&src[(size_t)row * 512 + c4];
  }
  __syncthreads();
  const int h = tid;
  const float* wp = W1 + (isenc ? 0 : (size_t)512 * 512) + h;
  float acc[8];
  float init = isenc ? 0.f : b1[h];
#pragma unroll
  for (int r = 0; r < 8; ++r) acc[r] = init;
#pragma unroll 4
  for (int k = 0; k < 512; ++k) {
    float wv = wp[(size_t)k * 512];
#pragma unroll
    for (int r = 0; r < 8; ++r) acc[r] = fmaf(xs[r][k], wv, acc[r]);
  }
  if (isenc) {
#pragma unroll
    for (int r = 0; r < 8; ++r) enc_proj[(size_t)(rows0 + r) * 512 + h] = acc[r];
  } else {
#pragma unroll
    for (int r = 0; r < 8; ++r) decb[(size_t)(rows0 + r) * 512 + h] = f2bf(acc[r]);
  }
}

// ---------------- Pass 2: W2 [512][2048] fp32 -> W2t [2048][512] bf16 ----------------
__global__ __launch_bounds__(256) void w2t_kernel(const float* __restrict__ W2,
                                                  unsigned short* __restrict__ W2t) {
  __shared__ unsigned short tile[32][33];
  int bn = blockIdx.x;
  int bk = blockIdx.y;
  int tx = threadIdx.x & 31;
  int ty = threadIdx.x >> 5;
#pragma unroll
  for (int i = 0; i < 32; i += 8)
    tile[ty + i][tx] = f2bf(W2[(size_t)(bk * 32 + ty + i) * 2048 + bn * 32 + tx]);
  __syncthreads();
#pragma unroll
  for (int i = 0; i < 32; i += 8)
    W2t[(size_t)(bn * 32 + ty + i) * 512 + bk * 32 + tx] = tile[tx][ty + i];
}

// ---------------- Pass 3: H[m][h] = tanh(encp[bt][h] + decb[bu][h]) bf16 ----------------
__global__ __launch_bounds__(256) void h_kernel(
    const float* __restrict__ encp, const unsigned short* __restrict__ decb,
    unsigned short* __restrict__ Hout) {
  int gid = blockIdx.x * 256 + threadIdx.x;
  int m = gid >> 6;
  int hc = (gid & 63) << 3;
  int bt = m >> 7;
  int bu = ((m >> 15) << 7) | (m & 127);
  u16x8 dv = *(const u16x8*)(decb + (size_t)bu * 512 + hc);
  f32x4 e0 = *(const f32x4*)(encp + (size_t)bt * 512 + hc);
  f32x4 e1 = *(const f32x4*)(encp + (size_t)bt * 512 + hc + 4);
  u16x8 hv;
#pragma unroll
  for (int j = 0; j < 4; ++j) hv[j] = f2bf(tanh_fast(bf2f(dv[j]) + e0[j]));
#pragma unroll
  for (int j = 0; j < 4; ++j) hv[4 + j] = f2bf(tanh_fast(bf2f(dv[4 + j]) + e1[j]));
  *(u16x8*)(Hout + (size_t)m * 512 + hc) = hv;
}

// ---------------- Pass 4: BM=128 BN=256 BK=32 ring-3 GEMM ----------------
// LDS per slot: A [128][32] bf16 (8 KB) + B [256][32] bf16 (16 KB) = 24 KB;
// ring-3 = 72 KB -> 2 blocks/CU. 8 waves (2M x 4N), wave-tile 64x64.
// Swizzle: 16B chunk c of row r at c ^ ((r>>1)&3) (PMC: 0 conflicts).
// Phase t: vmcnt(3) -> barrier -> ds_read 8 -> stage t+2 (3 gl16) -> 16 MFMA.
// Epilogue: 8 chunks of 16 rows via LDS [16][260] f32; per-row 1024B nt store.

__global__ __launch_bounds__(512, 4) void gemm32_kernel(
    const unsigned short* __restrict__ H,     // [131072][512] bf16
    const unsigned short* __restrict__ W2t,   // [2048][512] bf16
    const float* __restrict__ b2,             // [2048]
    float* __restrict__ out) {                // [131072][2048] fp32
  __shared__ __align__(1024) char smem[73728];

  const int bid = blockIdx.x;
  const int wg = (bid & 7) * 1024 + (bid >> 3);  // 8192%8==0 -> bijective
  const int my = wg >> 3;    // 0..1023 (A panel of 128 rows; 8 wg share it)
  const int ny = wg & 7;     // 0..7 (256-col block)

  const int tid = threadIdx.x;
  const int lane = tid & 63;
  const int w = tid >> 6;    // 0..7
  const int wm = w >> 2;     // 0..1
  const int wn = w & 3;      // 0..3
  const int fr = lane & 15;
  const int fq = lane >> 4;

  const char* ha = (const char*)(H + (size_t)my * 128 * 512);    // 128 rows x 1024B
  const char* wb = (const char*)(W2t + (size_t)ny * 256 * 512);  // 256 rows x 1024B

  // gl16 source offsets (dest linear; src chunk pre-swizzled):
  // A: 1 instr/wave (8KB region), B: 2 instrs/wave (16KB region)
  size_t srcA, srcB[2];
  {
    int d = w * 1024 + lane * 16;            // 0..8191
    int r = d >> 6;                          // row 0..127
    int c = (d >> 4) & 3;
    srcA = (size_t)r * 1024 + (size_t)((c ^ ((r >> 1) & 3)) << 4);
  }
#pragma unroll
  for (int p = 0; p < 2; ++p) {
    int d = p * 8192 + w * 1024 + lane * 16; // 0..16383 within B region
    int r = d >> 6;                          // row 0..255
    int c = (d >> 4) & 3;
    srcB[p] = (size_t)r * 1024 + (size_t)((c ^ ((r >> 1) & 3)) << 4);
  }

  // ds_read offsets within a slot (A at 0, B at 8192)
  const int swz = (fq ^ ((fr >> 1) & 3)) << 4;
  const int ldsA = (wm * 64 + fr) * 64 + swz;            // + mi*1024
  const int ldsB = 8192 + (wn * 64 + fr) * 64 + swz;     // + ni*1024

  f32x4 acc[4][4];
#pragma unroll
  for (int i = 0; i < 4; ++i)
#pragma unroll
    for (int j = 0; j < 4; ++j) acc[i][j] = (f32x4){0.f, 0.f, 0.f, 0.f};

#define STAGE(tt, slot)                                         \
  do {                                                          \
    char* sl = smem + (slot)*24576;                             \
    gl16(ha + srcA + (tt)*64, sl + w * 1024);                   \
    gl16(wb + srcB[0] + (tt)*64, sl + 8192 + w * 1024);         \
    gl16(wb + srcB[1] + (tt)*64, sl + 16384 + w * 1024);        \
  } while (0)

  STAGE(0, 0);
  STAGE(1, 1);

#pragma unroll
  for (int t = 0; t < 16; ++t) {
    if (t < 15) { VMCNT(3); } else { VMCNT(0); }
    BAR; MEMPIN;
    const char* As = smem + (t % 3) * 24576;
    bf16x8 a4[4], b4[4];
#pragma unroll
    for (int mi = 0; mi < 4; ++mi) a4[mi] = *(const bf16x8*)(As + ldsA + mi * 1024);
#pragma unroll
    for (int ni = 0; ni < 4; ++ni) b4[ni] = *(const bf16x8*)(As + ldsB + ni * 1024);
    if (t + 2 < 16) STAGE(t + 2, (t + 2) % 3);
    LGKM0;
    __builtin_amdgcn_s_setprio(1);
#pragma unroll
    for (int mi = 0; mi < 4; ++mi)
#pragma unroll
      for (int ni = 0; ni < 4; ++ni)
        acc[mi][ni] = __builtin_amdgcn_mfma_f32_16x16x32_bf16(
            a4[mi], b4[ni], acc[mi][ni], 0, 0, 0);
    __builtin_amdgcn_s_setprio(0);
  }
  BAR; MEMPIN;   // staging fully consumed; LDS reusable

  // ---- epilogue: 8 chunks of 16 rows; write -> BAR -> 1KB nt stores -> BAR ----
  float* lbuf = (float*)smem;                 // [16][260] f32 = 16.25 KB
  const size_t orow0 = (size_t)my * 128;
  const int ncol0 = ny * 256;
  float bvv[4];
#pragma unroll
  for (int ni = 0; ni < 4; ++ni) bvv[ni] = b2[ncol0 + wn * 64 + ni * 16 + fr];

#pragma unroll
  for (int c = 0; c < 8; ++c) {
    if ((c >> 2) == wm) {                     // 4 producer waves per chunk
      const int mi = c & 3;
#pragma unroll
      for (int ni = 0; ni < 4; ++ni)
#pragma unroll
        for (int r = 0; r < 4; ++r)
          lbuf[(fq * 4 + r) * 260 + wn * 64 + ni * 16 + fr] =
              acc[mi][ni][r] + bvv[ni];
    }
    LGKM0; BAR; MEMPIN;
    // all 8 waves: 2 rows each, one 1024B nt store per row
#pragma unroll
    for (int rr = 0; rr < 2; ++rr) {
      const int row = w * 2 + rr;
      f32x4 v = *(const f32x4*)&lbuf[row * 260 + lane * 4];
      __builtin_nontemporal_store(
          v, (f32x4*)&out[(orow0 + c * 16 + row) * 2048 + ncol0 + lane * 4]);
    }
    LGKM0; BAR; MEMPIN;                       // LDS reads done; buffer reusable
  }
#undef STAGE
}

extern "C" void kernel_launch(void* const* d_in, const int* in_sizes, int n_in,
                              void* d_out, int out_size, void* d_ws, size_t ws_size,
                              hipStream_t stream) {
  const float* enc = (const float*)d_in[0];
  const float* dec = (const float*)d_in[1];
  const float* W1  = (const float*)d_in[2];
  const float* b1  = (const float*)d_in[3];
  const float* W2  = (const float*)d_in[4];
  const float* b2  = (const float*)d_in[5];
  float* out = (float*)d_out;

  char* ws = (char*)d_ws;
  float* enc_proj = (float*)ws;                                    // 2 MB
  unsigned short* decb = (unsigned short*)(ws + (2u << 20));       // 512 KB
  unsigned short* W2t  = (unsigned short*)(ws + (2u << 20) + (512u << 10)); // 2 MB
  unsigned short* Hbuf = (unsigned short*)(ws + (8u << 20));       // 134.25 MB

  proj8_kernel<<<192, 512, 0, stream>>>(enc, dec, W1, b1, enc_proj, decb);
  w2t_kernel<<<dim3(64, 16), 256, 0, stream>>>(W2, W2t);
  h_kernel<<<32768, 256, 0, stream>>>(enc_proj, decb, Hbuf);
  gemm32_kernel<<<8192, 512, 0, stream>>>(Hbuf, W2t, b2, out);
}